// Round 16
// baseline (36.678 us; speedup 1.0000x reference)
//
#include <hip/hip_runtime.h>
#include <math.h>

#define NTHR 256
#define CF   4                       // frames per block
#define NBLK 2048                    // B * (F/CF) * quarters
#define B_ 4
#define F_ 512
#define N_ 1024
#define V_ 4
#define NSLOT 5                      // pred row slots

struct Partial {                     // 64 B, all f32
  float sum_diff2, sum_dist, sum_acc2, cnt;
  float gmin[3], gmax[3], pmin[3], pmax[3];
};

__device__ __forceinline__ void gl_lds16(const void* g, void* l) {
  __builtin_amdgcn_global_load_lds(
      (const __attribute__((address_space(1))) void*)g,
      (__attribute__((address_space(3))) void*)l, 16, 0, 0);
}

__global__ __launch_bounds__(NTHR) void loss_main(
    const float* __restrict__ pred, const float* __restrict__ gt,
    const int* __restrict__ vis, const float* __restrict__ P,
    const float* __restrict__ tracks, Partial* __restrict__ partials)
{
  __shared__ __align__(16) char sPred[NSLOT * 3072];   // 5 rotating row-slots
  __shared__ __align__(16) char sCons[2 * 4096];       // dbuf: gt 3072 | vis 1024
  __shared__ __align__(16) char sScr[1024];            // dummy DMA sink
  __shared__ Partial sw[NTHR / 64];

  // XCD-bijective swizzle (2048 % 8 == 0)
  const int bid = ((blockIdx.x & 7) << 8) | (blockIdx.x >> 3);
  const int b  = __builtin_amdgcn_readfirstlane(bid >> 9);
  const int fc = (bid >> 2) & 127;
  const int qr = bid & 3;
  const int f0 = fc << 2;
  const int n0 = qr << 8;
  const int t = threadIdx.x;
  const int wave = t >> 6, lane = t & 63;

  // projection matrices via uniform (scalar) loads
  float Pmv[V_][12];
#pragma unroll
  for (int v = 0; v < V_; ++v)
#pragma unroll
    for (int j = 0; j < 12; ++j)
      Pmv[v][j] = P[(v * B_ + b) * 12 + j];

  // ---- prologue A: pred rows f0..f0+2 (9 real + 3 dummy = 3 DMAs/wave)
  for (int c = wave; c < 12; c += 4) {
    const char* src; char* dst;
    if (c < 9) {
      const int r = c / 3, k = c - r * 3;
      src = (const char*)pred +
          ((size_t)(b * F_ + f0 + r) * N_ + n0) * 12 + (k << 10) + lane * 16;
      dst = sPred + r * 3072 + (k << 10);
    } else {
      src = (const char*)pred + lane * 16;
      dst = sScr;
    }
    gl_lds16(src, dst);
  }
  // ---- prologue B: cons frame f0 (gt 3 chunks + vis 1 = 1 DMA/wave)
  {
    const char* src; char* dst;
    if (wave < 3) {
      src = (const char*)gt +
          ((size_t)(b * F_ + f0) * N_ + n0) * 12 + (wave << 10) + lane * 16;
      dst = sCons + (wave << 10);
    } else {
      src = (const char*)vis + ((size_t)(b * F_ + f0) * N_ + n0) * 4 + lane * 16;
      dst = sCons + 3072;
    }
    gl_lds16(src, dst);
  }
  // ---- prologue C: tracks frame f0 direct (4 float2/thread)
  size_t fntc = ((size_t)f0 << 10) + n0 + t;
  float2 tk0c = *(const float2*)(tracks + ((((size_t)(0 * B_ + b) << 19) + fntc) << 1));
  float2 tk1c = *(const float2*)(tracks + ((((size_t)(1 * B_ + b) << 19) + fntc) << 1));
  float2 tk2c = *(const float2*)(tracks + ((((size_t)(2 * B_ + b) << 19) + fntc) << 1));
  float2 tk3c = *(const float2*)(tracks + ((((size_t)(3 * B_ + b) << 19) + fntc) << 1));

  float sum_diff2 = 0.0f, sum_dist = 0.0f, sum_acc2 = 0.0f, cntf = 0.0f;
  float gmin[3] = { INFINITY,  INFINITY,  INFINITY};
  float gmax[3] = {-INFINITY, -INFINITY, -INFINITY};
  float pmin[3] = { INFINITY,  INFINITY,  INFINITY};
  float pmax[3] = {-INFINITY, -INFINITY, -INFINITY};

#pragma unroll
  for (int i = 0; i < CF; ++i) {
    const int fi = f0 + i;
    const int fn1 = (fi + 1 < F_) ? fi + 1 : F_ - 1;   // clamped next frame

    // ---- issue NEXT frame tracks (4 VMEM)
    const size_t fntn = ((size_t)fn1 << 10) + n0 + t;
    const float2 tk0n = *(const float2*)(tracks + ((((size_t)(0 * B_ + b) << 19) + fntn) << 1));
    const float2 tk1n = *(const float2*)(tracks + ((((size_t)(1 * B_ + b) << 19) + fntn) << 1));
    const float2 tk2n = *(const float2*)(tracks + ((((size_t)(2 * B_ + b) << 19) + fntn) << 1));
    const float2 tk3n = *(const float2*)(tracks + ((((size_t)(3 * B_ + b) << 19) + fntn) << 1));

    // ---- issue NEXT frame cons DMA (1/wave) into sCons[(i+1)&1]
    {
      const char* src; char* dst;
      char* cd = sCons + ((i + 1) & 1) * 4096;
      if (wave < 3) {
        src = (const char*)gt +
            ((size_t)(b * F_ + fn1) * N_ + n0) * 12 + (wave << 10) + lane * 16;
        dst = cd + (wave << 10);
      } else {
        src = (const char*)vis + ((size_t)(b * F_ + fn1) * N_ + n0) * 4 + lane * 16;
        dst = cd + 3072;
      }
      gl_lds16(src, dst);
    }

    // ---- issue pred DMA row fi+3 into slot (i+3)%5 (1/wave, wave3 dummy)
    {
      const int rowPre = (fi + 3 < F_) ? fi + 3 : F_ - 1;
      const char* src; char* dst;
      if (wave < 3) {
        src = (const char*)pred +
            ((size_t)(b * F_ + rowPre) * N_ + n0) * 12 + (wave << 10) + lane * 16;
        dst = sPred + ((i + 3) % NSLOT) * 3072 + (wave << 10);
      } else {
        src = (const char*)pred + lane * 16;
        dst = sScr;
      }
      gl_lds16(src, dst);
    }

    // ---- counted wait: this iter's 6 issues stay in flight; older drained
    asm volatile("s_waitcnt vmcnt(6) lgkmcnt(0)\n\ts_barrier" ::: "memory");

    // ---- compute frame fi
    const float* s0 = (const float*)(sPred + ((i    ) % NSLOT) * 3072) + 3 * t;
    const float* s1 = (const float*)(sPred + ((i + 1) % NSLOT) * 3072) + 3 * t;
    const float* s2 = (const float*)(sPred + ((i + 2) % NSLOT) * 3072) + 3 * t;
    const char* cc = sCons + (i & 1) * 4096;
    const float* sG = (const float*)cc + 3 * t;
    const int   vm  = ((const int*)(cc + 3072))[t];
    const float px = s0[0], py = s0[1], pz = s0[2];
    const float gx = sG[0], gy = sG[1], gz = sG[2];

    pmin[0] = fminf(pmin[0], px); pmax[0] = fmaxf(pmax[0], px);
    pmin[1] = fminf(pmin[1], py); pmax[1] = fmaxf(pmax[1], py);
    pmin[2] = fminf(pmin[2], pz); pmax[2] = fmaxf(pmax[2], pz);

    const float vmf = vm ? 1.0f : 0.0f;
    const float d0 = px - gx, d1 = py - gy, d2 = pz - gz;
    sum_diff2 += vmf * (d0 * d0 + d1 * d1 + d2 * d2);
    cntf += vmf;
    gmin[0] = fminf(gmin[0], vm ? gx :  INFINITY);
    gmax[0] = fmaxf(gmax[0], vm ? gx : -INFINITY);
    gmin[1] = fminf(gmin[1], vm ? gy :  INFINITY);
    gmax[1] = fmaxf(gmax[1], vm ? gy : -INFINITY);
    gmin[2] = fminf(gmin[2], vm ? gz :  INFINITY);
    gmax[2] = fmaxf(gmax[2], vm ? gz : -INFINITY);

    const float am = (fi < F_ - 2) ? 1.0f : 0.0f;
    const float a0 = s2[0] - 2.0f * s1[0] + px;
    const float a1 = s2[1] - 2.0f * s1[1] + py;
    const float a2 = s2[2] - 2.0f * s1[2] + pz;
    sum_acc2 += am * (a0 * a0 + a1 * a1 + a2 * a2);

    const float2 tks[V_] = {tk0c, tk1c, tk2c, tk3c};
#pragma unroll
    for (int v = 0; v < V_; ++v) {
      const float h0 = Pmv[v][0] * px + Pmv[v][1] * py + Pmv[v][2]  * pz + Pmv[v][3];
      const float h1 = Pmv[v][4] * px + Pmv[v][5] * py + Pmv[v][6]  * pz + Pmv[v][7];
      const float h2 = Pmv[v][8] * px + Pmv[v][9] * py + Pmv[v][10] * pz + Pmv[v][11];
      const float inv = __builtin_amdgcn_rcpf(h2 + 1e-10f);
      const float dx = h0 * inv - tks[v].x;
      const float dy = h1 * inv - tks[v].y;
      sum_dist += dx * dx + dy * dy;
    }

    // rotate pipelined track registers
    tk0c = tk0n; tk1c = tk1n; tk2c = tk2n; tk3c = tk3n;
  }

  // ---------------- wave shuffle reduction (f32, deterministic tree)
#pragma unroll
  for (int o = 32; o > 0; o >>= 1) {
    sum_diff2 += __shfl_down(sum_diff2, o);
    sum_dist  += __shfl_down(sum_dist,  o);
    sum_acc2  += __shfl_down(sum_acc2,  o);
    cntf      += __shfl_down(cntf,      o);
#pragma unroll
    for (int k = 0; k < 3; ++k) {
      gmin[k] = fminf(gmin[k], __shfl_down(gmin[k], o));
      gmax[k] = fmaxf(gmax[k], __shfl_down(gmax[k], o));
      pmin[k] = fminf(pmin[k], __shfl_down(pmin[k], o));
      pmax[k] = fmaxf(pmax[k], __shfl_down(pmax[k], o));
    }
  }

  if (lane == 0) {
    Partial p;
    p.sum_diff2 = sum_diff2; p.sum_dist = sum_dist;
    p.sum_acc2  = sum_acc2;  p.cnt      = cntf;
#pragma unroll
    for (int k = 0; k < 3; ++k) {
      p.gmin[k] = gmin[k]; p.gmax[k] = gmax[k];
      p.pmin[k] = pmin[k]; p.pmax[k] = pmax[k];
    }
    sw[wave] = p;
  }
  __syncthreads();
  if (t == 0) {
    Partial p = sw[0];
#pragma unroll
    for (int w = 1; w < NTHR / 64; ++w) {
      p.sum_diff2 += sw[w].sum_diff2; p.sum_dist += sw[w].sum_dist;
      p.sum_acc2  += sw[w].sum_acc2;  p.cnt      += sw[w].cnt;
#pragma unroll
      for (int k = 0; k < 3; ++k) {
        p.gmin[k] = fminf(p.gmin[k], sw[w].gmin[k]);
        p.gmax[k] = fmaxf(p.gmax[k], sw[w].gmax[k]);
        p.pmin[k] = fminf(p.pmin[k], sw[w].pmin[k]);
        p.pmax[k] = fmaxf(p.pmax[k], sw[w].pmax[k]);
      }
    }
    partials[bid] = p;
  }
}

__global__ __launch_bounds__(NTHR) void loss_final(
    const Partial* __restrict__ partials, float* __restrict__ out)
{
  float sum_diff2 = 0.0f, sum_dist = 0.0f, sum_acc2 = 0.0f, cnt = 0.0f;
  float gmin[3] = { INFINITY,  INFINITY,  INFINITY};
  float gmax[3] = {-INFINITY, -INFINITY, -INFINITY};
  float pmin[3] = { INFINITY,  INFINITY,  INFINITY};
  float pmax[3] = {-INFINITY, -INFINITY, -INFINITY};

  const int tid = threadIdx.x;
  for (int i = tid; i < NBLK; i += NTHR) {   // fixed order -> deterministic
    const Partial p = partials[i];
    sum_diff2 += p.sum_diff2; sum_dist += p.sum_dist;
    sum_acc2  += p.sum_acc2;  cnt      += p.cnt;
#pragma unroll
    for (int k = 0; k < 3; ++k) {
      gmin[k] = fminf(gmin[k], p.gmin[k]); gmax[k] = fmaxf(gmax[k], p.gmax[k]);
      pmin[k] = fminf(pmin[k], p.pmin[k]); pmax[k] = fmaxf(pmax[k], p.pmax[k]);
    }
  }

#pragma unroll
  for (int o = 32; o > 0; o >>= 1) {
    sum_diff2 += __shfl_down(sum_diff2, o);
    sum_dist  += __shfl_down(sum_dist,  o);
    sum_acc2  += __shfl_down(sum_acc2,  o);
    cnt       += __shfl_down(cnt,       o);
#pragma unroll
    for (int k = 0; k < 3; ++k) {
      gmin[k] = fminf(gmin[k], __shfl_down(gmin[k], o));
      gmax[k] = fmaxf(gmax[k], __shfl_down(gmax[k], o));
      pmin[k] = fminf(pmin[k], __shfl_down(pmin[k], o));
      pmax[k] = fmaxf(pmax[k], __shfl_down(pmax[k], o));
    }
  }

  __shared__ Partial sw[NTHR / 64];
  const int lane = tid & 63;
  const int wave = tid >> 6;
  if (lane == 0) {
    Partial p;
    p.sum_diff2 = sum_diff2; p.sum_dist = sum_dist;
    p.sum_acc2  = sum_acc2;  p.cnt      = cnt;
#pragma unroll
    for (int k = 0; k < 3; ++k) {
      p.gmin[k] = gmin[k]; p.gmax[k] = gmax[k];
      p.pmin[k] = pmin[k]; p.pmax[k] = pmax[k];
    }
    sw[wave] = p;
  }
  __syncthreads();

  if (tid == 0) {
    Partial p = sw[0];
#pragma unroll
    for (int w = 1; w < NTHR / 64; ++w) {
      p.sum_diff2 += sw[w].sum_diff2; p.sum_dist += sw[w].sum_dist;
      p.sum_acc2  += sw[w].sum_acc2;  p.cnt      += sw[w].cnt;
#pragma unroll
      for (int k = 0; k < 3; ++k) {
        p.gmin[k] = fminf(p.gmin[k], sw[w].gmin[k]);
        p.gmax[k] = fmaxf(p.gmax[k], sw[w].gmax[k]);
        p.pmin[k] = fminf(p.pmin[k], sw[w].pmin[k]);
        p.pmax[k] = fmaxf(p.pmax[k], sw[w].pmax[k]);
      }
    }

    double sr = -INFINITY;
#pragma unroll
    for (int k = 0; k < 3; ++k) sr = fmax(sr, (double)p.gmax[k] - (double)p.gmin[k]);
    sr += 1e-6;
    const double recon = (double)p.sum_diff2 / fmax((double)p.cnt * 3.0, 1.0) / (sr * sr);

    const double ident = (double)p.sum_dist / 224.0 / ((double)V_ * B_ * F_ * N_ * 2.0);

    double st = -INFINITY;
#pragma unroll
    for (int k = 0; k < 3; ++k) st = fmax(st, (double)p.pmax[k] - (double)p.pmin[k]);
    st += 1e-6;
    const double tloss = (double)p.sum_acc2 / ((double)B_ * (F_ - 2) * N_);
    const double temp = tloss / (st * st);

    const double total = recon + ident + 0.5 * temp;
    out[0] = (float)total;
    out[1] = (float)recon;
    out[2] = (float)ident;
    out[3] = (float)temp;
  }
}

extern "C" void kernel_launch(void* const* d_in, const int* in_sizes, int n_in,
                              void* d_out, int out_size, void* d_ws, size_t ws_size,
                              hipStream_t stream) {
  const float* pred   = (const float*)d_in[0];
  const float* gt     = (const float*)d_in[1];
  const int*   vis    = (const int*)d_in[2];
  const float* P      = (const float*)d_in[3];
  const float* tracks = (const float*)d_in[4];
  float* out = (float*)d_out;
  Partial* partials = (Partial*)d_ws;   // 2048 * 64 B = 128 KB

  loss_main<<<NBLK, NTHR, 0, stream>>>(pred, gt, vis, P, tracks, partials);
  loss_final<<<1, NTHR, 0, stream>>>(partials, out);
}

// Round 17
// 33.374 us; speedup vs baseline: 1.0990x; 1.0990x over previous
//
#include <hip/hip_runtime.h>
#include <math.h>

#define NTHR 256
#define B_ 4
#define F_ 512
#define N_ 1024
#define V_ 4
#define GSTR (F_ * N_)               // 524288 = points per batch (loop stride)
#define NBLK (GSTR / NTHR)           // 2048 blocks, 4 pts/thread (one per batch)

struct Partial {                     // 64 B, all f32
  float sum_diff2, sum_dist, sum_acc2, cnt;
  float gmin[3], gmax[3], pmin[3], pmax[3];
};

__global__ __launch_bounds__(NTHR) void loss_main(
    const float* __restrict__ pred, const float* __restrict__ gt,
    const int* __restrict__ vis, const float* __restrict__ P,
    const float* __restrict__ tracks, Partial* __restrict__ partials)
{
  __shared__ float sP[B_ * V_ * 12];          // all 16 mats
  __shared__ Partial sw[NTHR / 64];

  // XCD swizzle: 2048 blocks -> 256 consecutive blocks per XCD (bijective)
  const int bid = ((blockIdx.x & 7) << 8) + (blockIdx.x >> 3);
  const int t = threadIdx.x;
  const int g = (bid << 8) + t;               // point within batch [0, 524288)
  const int f = g >> 10;                      // wave-uniform

  if (t < B_ * V_ * 12) sP[t] = P[t];         // P is [V][B][3][4] = 192 floats
  __syncthreads();

  // loop-invariant pieces
  const int d1 = (f + 1 < F_) ? N_ : 0;       // clamped neighbor offsets (points)
  const int d2 = (f + 2 < F_) ? 2 * N_ : 0;
  const float am = (f < F_ - 2) ? 1.0f : 0.0f;

  float sum_diff2 = 0.0f, sum_dist = 0.0f, sum_acc2 = 0.0f, cntf = 0.0f;
  float gmin[3] = { INFINITY,  INFINITY,  INFINITY};
  float gmax[3] = {-INFINITY, -INFINITY, -INFINITY};
  float pmin[3] = { INFINITY,  INFINITY,  INFINITY};
  float pmax[3] = {-INFINITY, -INFINITY, -INFINITY};

#pragma unroll
  for (int b = 0; b < B_; ++b) {              // stride = one full batch
    const size_t e = (size_t)b * GSTR + g;    // point id

    // ---- all loads up front, independent, coalesced
    const float* pp = pred + e * 3;
    const float px = pp[0], py = pp[1], pz = pp[2];

    const float* gp = gt + e * 3;
    const float gx = gp[0], gy = gp[1], gz = gp[2];

    const int vm = vis[e];

    const float* q1 = pred + (e + d1) * 3;
    const float n1x = q1[0], n1y = q1[1], n1z = q1[2];
    const float* q2 = pred + (e + d2) * 3;
    const float n2x = q2[0], n2y = q2[1], n2z = q2[2];

    const float2 tk0 = *(const float2*)(tracks + ((((size_t)(0 * B_ + b) << 19) + g) << 1));
    const float2 tk1 = *(const float2*)(tracks + ((((size_t)(1 * B_ + b) << 19) + g) << 1));
    const float2 tk2 = *(const float2*)(tracks + ((((size_t)(2 * B_ + b) << 19) + g) << 1));
    const float2 tk3 = *(const float2*)(tracks + ((((size_t)(3 * B_ + b) << 19) + g) << 1));

    // ---- compute (branchless)
    const float vmf = vm ? 1.0f : 0.0f;
    const float dd0 = px - gx, dd1 = py - gy, dd2 = pz - gz;
    sum_diff2 += vmf * (dd0 * dd0 + dd1 * dd1 + dd2 * dd2);
    cntf += vmf;
    gmin[0] = fminf(gmin[0], vm ? gx :  INFINITY);
    gmax[0] = fmaxf(gmax[0], vm ? gx : -INFINITY);
    gmin[1] = fminf(gmin[1], vm ? gy :  INFINITY);
    gmax[1] = fmaxf(gmax[1], vm ? gy : -INFINITY);
    gmin[2] = fminf(gmin[2], vm ? gz :  INFINITY);
    gmax[2] = fmaxf(gmax[2], vm ? gz : -INFINITY);
    pmin[0] = fminf(pmin[0], px); pmax[0] = fmaxf(pmax[0], px);
    pmin[1] = fminf(pmin[1], py); pmax[1] = fmaxf(pmax[1], py);
    pmin[2] = fminf(pmin[2], pz); pmax[2] = fmaxf(pmax[2], pz);

    const float a0 = n2x - 2.0f * n1x + px;
    const float a1 = n2y - 2.0f * n1y + py;
    const float a2 = n2z - 2.0f * n1z + pz;
    sum_acc2 += am * (a0 * a0 + a1 * a1 + a2 * a2);

    const float2 tks[V_] = {tk0, tk1, tk2, tk3};
#pragma unroll
    for (int v = 0; v < V_; ++v) {
      const float* Pm = sP + (v * B_ + b) * 12;
      const float h0 = Pm[0] * px + Pm[1] * py + Pm[2]  * pz + Pm[3];
      const float h1 = Pm[4] * px + Pm[5] * py + Pm[6]  * pz + Pm[7];
      const float h2 = Pm[8] * px + Pm[9] * py + Pm[10] * pz + Pm[11];
      const float inv = __builtin_amdgcn_rcpf(h2 + 1e-10f);
      const float dx = h0 * inv - tks[v].x;
      const float dy = h1 * inv - tks[v].y;
      sum_dist += dx * dx + dy * dy;
    }
  }

  // ---- wave shuffle reduction (deterministic tree), amortized over 4 pts
#pragma unroll
  for (int o = 32; o > 0; o >>= 1) {
    sum_diff2 += __shfl_down(sum_diff2, o);
    sum_dist  += __shfl_down(sum_dist,  o);
    sum_acc2  += __shfl_down(sum_acc2,  o);
    cntf      += __shfl_down(cntf,      o);
#pragma unroll
    for (int k = 0; k < 3; ++k) {
      gmin[k] = fminf(gmin[k], __shfl_down(gmin[k], o));
      gmax[k] = fmaxf(gmax[k], __shfl_down(gmax[k], o));
      pmin[k] = fminf(pmin[k], __shfl_down(pmin[k], o));
      pmax[k] = fmaxf(pmax[k], __shfl_down(pmax[k], o));
    }
  }

  const int wave = t >> 6, lane = t & 63;
  if (lane == 0) {
    Partial p;
    p.sum_diff2 = sum_diff2; p.sum_dist = sum_dist;
    p.sum_acc2  = sum_acc2;  p.cnt      = cntf;
#pragma unroll
    for (int k = 0; k < 3; ++k) {
      p.gmin[k] = gmin[k]; p.gmax[k] = gmax[k];
      p.pmin[k] = pmin[k]; p.pmax[k] = pmax[k];
    }
    sw[wave] = p;
  }
  __syncthreads();
  if (t == 0) {
    Partial p = sw[0];
#pragma unroll
    for (int w = 1; w < NTHR / 64; ++w) {
      p.sum_diff2 += sw[w].sum_diff2; p.sum_dist += sw[w].sum_dist;
      p.sum_acc2  += sw[w].sum_acc2;  p.cnt      += sw[w].cnt;
#pragma unroll
      for (int k = 0; k < 3; ++k) {
        p.gmin[k] = fminf(p.gmin[k], sw[w].gmin[k]);
        p.gmax[k] = fmaxf(p.gmax[k], sw[w].gmax[k]);
        p.pmin[k] = fminf(p.pmin[k], sw[w].pmin[k]);
        p.pmax[k] = fmaxf(p.pmax[k], sw[w].pmax[k]);
      }
    }
    partials[bid] = p;
  }
}

__global__ __launch_bounds__(NTHR) void loss_final(
    const Partial* __restrict__ partials, float* __restrict__ out)
{
  float sum_diff2 = 0.0f, sum_dist = 0.0f, sum_acc2 = 0.0f, cnt = 0.0f;
  float gmin[3] = { INFINITY,  INFINITY,  INFINITY};
  float gmax[3] = {-INFINITY, -INFINITY, -INFINITY};
  float pmin[3] = { INFINITY,  INFINITY,  INFINITY};
  float pmax[3] = {-INFINITY, -INFINITY, -INFINITY};

  const int tid = threadIdx.x;
  for (int i = tid; i < NBLK; i += NTHR) {   // fixed order -> deterministic
    const Partial p = partials[i];
    sum_diff2 += p.sum_diff2; sum_dist += p.sum_dist;
    sum_acc2  += p.sum_acc2;  cnt      += p.cnt;
#pragma unroll
    for (int k = 0; k < 3; ++k) {
      gmin[k] = fminf(gmin[k], p.gmin[k]); gmax[k] = fmaxf(gmax[k], p.gmax[k]);
      pmin[k] = fminf(pmin[k], p.pmin[k]); pmax[k] = fmaxf(pmax[k], p.pmax[k]);
    }
  }

#pragma unroll
  for (int o = 32; o > 0; o >>= 1) {
    sum_diff2 += __shfl_down(sum_diff2, o);
    sum_dist  += __shfl_down(sum_dist,  o);
    sum_acc2  += __shfl_down(sum_acc2,  o);
    cnt       += __shfl_down(cnt,       o);
#pragma unroll
    for (int k = 0; k < 3; ++k) {
      gmin[k] = fminf(gmin[k], __shfl_down(gmin[k], o));
      gmax[k] = fmaxf(gmax[k], __shfl_down(gmax[k], o));
      pmin[k] = fminf(pmin[k], __shfl_down(pmin[k], o));
      pmax[k] = fmaxf(pmax[k], __shfl_down(pmax[k], o));
    }
  }

  __shared__ Partial sw[NTHR / 64];
  const int lane = tid & 63;
  const int wave = tid >> 6;
  if (lane == 0) {
    Partial p;
    p.sum_diff2 = sum_diff2; p.sum_dist = sum_dist;
    p.sum_acc2  = sum_acc2;  p.cnt      = cnt;
#pragma unroll
    for (int k = 0; k < 3; ++k) {
      p.gmin[k] = gmin[k]; p.gmax[k] = gmax[k];
      p.pmin[k] = pmin[k]; p.pmax[k] = pmax[k];
    }
    sw[wave] = p;
  }
  __syncthreads();

  if (tid == 0) {
    Partial p = sw[0];
#pragma unroll
    for (int w = 1; w < NTHR / 64; ++w) {
      p.sum_diff2 += sw[w].sum_diff2; p.sum_dist += sw[w].sum_dist;
      p.sum_acc2  += sw[w].sum_acc2;  p.cnt      += sw[w].cnt;
#pragma unroll
      for (int k = 0; k < 3; ++k) {
        p.gmin[k] = fminf(p.gmin[k], sw[w].gmin[k]);
        p.gmax[k] = fmaxf(p.gmax[k], sw[w].gmax[k]);
        p.pmin[k] = fminf(p.pmin[k], sw[w].pmin[k]);
        p.pmax[k] = fmaxf(p.pmax[k], sw[w].pmax[k]);
      }
    }

    double sr = -INFINITY;
#pragma unroll
    for (int k = 0; k < 3; ++k) sr = fmax(sr, (double)p.gmax[k] - (double)p.gmin[k]);
    sr += 1e-6;
    const double recon = (double)p.sum_diff2 / fmax((double)p.cnt * 3.0, 1.0) / (sr * sr);

    const double ident = (double)p.sum_dist / 224.0 / ((double)V_ * B_ * F_ * N_ * 2.0);

    double st = -INFINITY;
#pragma unroll
    for (int k = 0; k < 3; ++k) st = fmax(st, (double)p.pmax[k] - (double)p.pmin[k]);
    st += 1e-6;
    const double tloss = (double)p.sum_acc2 / ((double)B_ * (F_ - 2) * N_);
    const double temp = tloss / (st * st);

    const double total = recon + ident + 0.5 * temp;
    out[0] = (float)total;
    out[1] = (float)recon;
    out[2] = (float)ident;
    out[3] = (float)temp;
  }
}

extern "C" void kernel_launch(void* const* d_in, const int* in_sizes, int n_in,
                              void* d_out, int out_size, void* d_ws, size_t ws_size,
                              hipStream_t stream) {
  const float* pred   = (const float*)d_in[0];
  const float* gt     = (const float*)d_in[1];
  const int*   vis    = (const int*)d_in[2];
  const float* P      = (const float*)d_in[3];
  const float* tracks = (const float*)d_in[4];
  float* out = (float*)d_out;
  Partial* partials = (Partial*)d_ws;   // 2048 * 64 B = 128 KB

  loss_main<<<NBLK, NTHR, 0, stream>>>(pred, gt, vis, P, tracks, partials);
  loss_final<<<1, NTHR, 0, stream>>>(partials, out);
}